// Round 1
// baseline (1321.379 us; speedup 1.0000x reference)
//
#include <hip/hip_runtime.h>
#include <cstdint>
#include <cstddef>

#define BB 256
#define TT 250
#define DIN 700
#define H1 256
#define H2 256
#define DOUT 20
#define BJ0 0.01f
#define BETAC 1.8f

// ---------------------------------------------------------------------------
// Generic small transpose: in is R x C row-major, out is C x R row-major,
// out[c*R + r] = in[r*C + c]. Tiny matrices; launch cost negligible.
// ---------------------------------------------------------------------------
__global__ void transpose_k(const float* __restrict__ in, float* __restrict__ out,
                            int R, int C) {
    int i = blockIdx.x * blockDim.x + threadIdx.x;
    int n = R * C;
    if (i < n) {
        int c = i / R;
        int r = i - c * R;
        out[i] = in[r * C + c];
    }
}

// ---------------------------------------------------------------------------
// Phase 1: Xp[t][b][h] = b_h1[h] + sum_{d: x[b,t,d]!=0} wT1[d*H1 + h]
// One wave per (b,t) pair; lane l covers h = 4l..4l+3 via float4.
// Active-d list built wave-locally with ballot (deterministic, ordered).
// ---------------------------------------------------------------------------
__global__ __launch_bounds__(256) void xproj_k(const float* __restrict__ x,
                                               const float* __restrict__ wT1,
                                               const float* __restrict__ b_h1,
                                               float* __restrict__ Xp) {
    const int lane = threadIdx.x & 63;
    const int wv   = threadIdx.x >> 6;
    const int bt   = blockIdx.x * 4 + wv;   // grid = T*B/4 = 16000
    const int b    = bt & (BB - 1);
    const int t    = bt >> 8;

    __shared__ int lst[4][704];

    const float* xrow = x + ((size_t)b * TT + t) * DIN;
    int cnt = 0;
    for (int c = 0; c < 11; ++c) {
        int d = c * 64 + lane;
        bool p = (d < DIN) && (xrow[d] != 0.0f);
        unsigned long long m = __ballot(p ? 1 : 0);
        if (p) {
            int pos = cnt + __popcll(m & ((1ull << lane) - 1ull));
            lst[wv][pos] = d;
        }
        cnt += __popcll(m);
    }
    __syncthreads();   // make each wave's LDS list visible to itself safely

    float4 acc = *(const float4*)(b_h1 + lane * 4);
    for (int k = 0; k < cnt; ++k) {
        int j = lst[wv][k];
        const float4 w = *(const float4*)(wT1 + (size_t)j * H1 + lane * 4);
        acc.x += w.x; acc.y += w.y; acc.z += w.z; acc.w += w.w;
    }
    *(float4*)(Xp + ((size_t)t * BB + b) * H1 + lane * 4) = acc;
}

// ---------------------------------------------------------------------------
// Phase 2: recurrent loop. One block per batch element, thread h = neuron h.
// All state in registers; spike index lists in LDS, deterministic order via
// ballot + popcount prefix. Weight gathers are coalesced reads of wT rows.
// ---------------------------------------------------------------------------
__global__ __launch_bounds__(256) void rec_k(
    const float* __restrict__ Xp,
    const float* __restrict__ wT11, const float* __restrict__ wT12,
    const float* __restrict__ wT22, const float* __restrict__ wT2o,
    const float* __restrict__ b_h2, const float* __restrict__ b_o,
    const float* __restrict__ tau_adp_h1, const float* __restrict__ tau_adp_h2,
    const float* __restrict__ tau_m_h1, const float* __restrict__ tau_m_h2,
    const float* __restrict__ tau_m_o,
    float* __restrict__ out) {
    const int b    = blockIdx.x;
    const int h    = threadIdx.x;
    const int lane = h & 63;
    const int wv   = h >> 6;

    __shared__ int lst1[H1];
    __shared__ int lst2[H2];
    __shared__ unsigned long long wmask[4];
    __shared__ float smo[DOUT];

    const float alpha1 = expf(-1.0f / tau_m_h1[h]);
    const float ro1    = expf(-1.0f / tau_adp_h1[h]);
    const float alpha2 = expf(-1.0f / tau_m_h2[h]);
    const float ro2    = expf(-1.0f / tau_adp_h2[h]);
    const float bh2v   = b_h2[h];

    float mem1 = 0.f, spk1 = 0.f, bb1 = BJ0;
    float mem2 = 0.f, spk2 = 0.f, bb2 = BJ0;
    float alpo = 0.f, bov = 0.f, memo = 0.f, accs = 0.f;
    if (h < DOUT) {
        alpo = expf(-1.0f / tau_m_o[h]);
        bov  = b_o[h];
    }
    int n1 = 0, n2 = 0;

    for (int t = 0; t < TT; ++t) {
        // ---- layer 1 input: precomputed feedforward + recurrent gather ----
        float h1in = Xp[((size_t)t * BB + b) * H1 + h];
        #pragma unroll 4
        for (int k = 0; k < n1; ++k) h1in += wT11[(size_t)lst1[k] * H1 + h];

        bb1  = ro1 * bb1 + BETAC * (1.f - ro1) * spk1;
        mem1 = mem1 * alpha1 - bb1 * spk1 + (1.f - alpha1) * h1in;
        float ns1 = (mem1 - bb1 - BJ0) > 0.f ? 1.f : 0.f;
        spk1 = ns1;

        __syncthreads();                       // everyone done reading lst1
        unsigned long long m1 = __ballot(ns1 != 0.f ? 1 : 0);
        if (lane == 0) wmask[wv] = m1;
        __syncthreads();
        {
            int pos = __popcll(m1 & ((1ull << lane) - 1ull));
            int tot = 0;
            for (int w = 0; w < 4; ++w) {
                unsigned long long mw = wmask[w];
                if (w < wv) pos += __popcll(mw);
                tot += __popcll(mw);
            }
            if (ns1 != 0.f) lst1[pos] = h;
            n1 = tot;
        }
        __syncthreads();                       // lst1/n1 ready

        // ---- layer 2 input: two recurrent gathers ----
        float h2in = bh2v;
        #pragma unroll 4
        for (int k = 0; k < n1; ++k) h2in += wT12[(size_t)lst1[k] * H1 + h];
        #pragma unroll 4
        for (int k = 0; k < n2; ++k) h2in += wT22[(size_t)lst2[k] * H1 + h];

        bb2  = ro2 * bb2 + BETAC * (1.f - ro2) * spk2;
        mem2 = mem2 * alpha2 - bb2 * spk2 + (1.f - alpha2) * h2in;
        float ns2 = (mem2 - bb2 - BJ0) > 0.f ? 1.f : 0.f;
        spk2 = ns2;

        __syncthreads();                       // everyone done reading lst2
        unsigned long long m2 = __ballot(ns2 != 0.f ? 1 : 0);
        if (lane == 0) wmask[wv] = m2;
        __syncthreads();
        {
            int pos = __popcll(m2 & ((1ull << lane) - 1ull));
            int tot = 0;
            for (int w = 0; w < 4; ++w) {
                unsigned long long mw = wmask[w];
                if (w < wv) pos += __popcll(mw);
                tot += __popcll(mw);
            }
            if (ns2 != 0.f) lst2[pos] = h;
            n2 = tot;
        }
        __syncthreads();                       // lst2/n2 ready

        // ---- output neuron + online softmax accumulation ----
        if (h < DOUT) {
            float oin = bov;
            for (int k = 0; k < n2; ++k) oin += wT2o[lst2[k] * DOUT + h];
            memo = memo * alpo + (1.f - alpo) * oin;
            smo[h] = memo;
        }
        __syncthreads();
        if (h < DOUT) {
            float mx = smo[0];
            for (int i = 1; i < DOUT; ++i) mx = fmaxf(mx, smo[i]);
            float s = 0.f;
            for (int i = 0; i < DOUT; ++i) s += expf(smo[i] - mx);
            accs += expf(memo - mx) / s;
        }
        // no trailing barrier needed: smo is next written by the same threads
        // only after they pass the next iteration's barriers
    }
    if (h < DOUT) out[b * DOUT + h] = accs;
}

// ---------------------------------------------------------------------------
// Workspace layout (floats):
//   wT1   [700*256] = 179200
//   wT11  [256*256] =  65536
//   wT12  [256*256] =  65536
//   wT22  [256*256] =  65536
//   wT2o  [256*20]  =   5120
//   Xp    [250*256*256] = 16384000
// total ~67.1 MB
// ---------------------------------------------------------------------------
extern "C" void kernel_launch(void* const* d_in, const int* in_sizes, int n_in,
                              void* d_out, int out_size, void* d_ws, size_t ws_size,
                              hipStream_t stream) {
    const float* x          = (const float*)d_in[0];
    const float* w_i2h1     = (const float*)d_in[1];
    const float* w_h12h1    = (const float*)d_in[2];
    const float* w_h12h2    = (const float*)d_in[3];
    const float* w_h22h2    = (const float*)d_in[4];
    const float* w_h2o      = (const float*)d_in[5];
    const float* b_h1       = (const float*)d_in[6];
    const float* b_h2       = (const float*)d_in[7];
    const float* b_o        = (const float*)d_in[8];
    const float* tau_adp_h1 = (const float*)d_in[9];
    const float* tau_adp_h2 = (const float*)d_in[10];
    const float* tau_m_h1   = (const float*)d_in[11];
    const float* tau_m_h2   = (const float*)d_in[12];
    const float* tau_m_o    = (const float*)d_in[13];

    float* ws   = (float*)d_ws;
    float* wT1  = ws;
    float* wT11 = wT1  + 179200;
    float* wT12 = wT11 + 65536;
    float* wT22 = wT12 + 65536;
    float* wT2o = wT22 + 65536;
    float* Xp   = wT2o + 5120;

    transpose_k<<<(179200 + 255) / 256, 256, 0, stream>>>(w_i2h1,  wT1,  H1,  DIN);
    transpose_k<<<(65536  + 255) / 256, 256, 0, stream>>>(w_h12h1, wT11, H1,  H1);
    transpose_k<<<(65536  + 255) / 256, 256, 0, stream>>>(w_h12h2, wT12, H2,  H1);
    transpose_k<<<(65536  + 255) / 256, 256, 0, stream>>>(w_h22h2, wT22, H2,  H2);
    transpose_k<<<(5120   + 255) / 256, 256, 0, stream>>>(w_h2o,   wT2o, DOUT, H2);

    xproj_k<<<(TT * BB) / 4, 256, 0, stream>>>(x, wT1, b_h1, Xp);

    rec_k<<<BB, 256, 0, stream>>>(Xp, wT11, wT12, wT22, wT2o,
                                  b_h2, b_o, tau_adp_h1, tau_adp_h2,
                                  tau_m_h1, tau_m_h2, tau_m_o,
                                  (float*)d_out);
}